// Round 1
// baseline (9535.112 us; speedup 1.0000x reference)
//
#include <hip/hip_runtime.h>

#define NSAMP  32768
#define D      512
#define RPB    8          // samples per workgroup
#define MT     40         // state rows = 5 * RPB  (h + 4 Jacobian rows per sample)
#define BK     16         // k-chunk of streamed weight tile
#define NCHUNK (D / BK)   // 32
#define NLAYER 7          // hidden blocks (WIDTH-1)

__device__ __forceinline__ float4 ld4(const float* p) { return *(const float4*)p; }

__global__ __launch_bounds__(256, 1)
void mlp_curl_fwd(const float* __restrict__ x,
                  const float* __restrict__ W0,
                  const float* __restrict__ b0,
                  const float* __restrict__ Wh,
                  const float* __restrict__ bh,
                  const float* __restrict__ Wf,
                  float* __restrict__ out)
{
    // State: rows 0..7 = h of samples 0..7; row 8+i*8+r = J_i of sample r.
    __shared__ float S[MT][D];        // 80 KB
    __shared__ float Wt[2][BK * D];   // 64 KB, double-buffered weight chunk
    __shared__ float JL[RPB][4][4];   // final per-sample 4x4 Jacobian

    const int t    = threadIdx.x;
    const int g    = t >> 6;     // wave id 0..3 -> owns state rows 10g..10g+9
    const int lane = t & 63;
    const int n0   = blockIdx.x * RPB;

    // ---------- init: h0 = x@W0 + b0 (NO tanh, faithful); J0 = W0 ----------
    {
        const int r  = t >> 5;           // 0..7
        const int c0 = (t & 31) << 2;    // 0..124
        const float4 xv = ld4(x + (size_t)(n0 + r) * 4);
        #pragma unroll
        for (int q = 0; q < 4; ++q) {
            const int j = c0 + (q << 7);
            float4 w0k[4];
            #pragma unroll
            for (int k = 0; k < 4; ++k) w0k[k] = ld4(W0 + k * D + j);
            float4 h = ld4(b0 + j);
            h.x += xv.x * w0k[0].x + xv.y * w0k[1].x + xv.z * w0k[2].x + xv.w * w0k[3].x;
            h.y += xv.x * w0k[0].y + xv.y * w0k[1].y + xv.z * w0k[2].y + xv.w * w0k[3].y;
            h.z += xv.x * w0k[0].z + xv.y * w0k[1].z + xv.z * w0k[2].z + xv.w * w0k[3].z;
            h.w += xv.x * w0k[0].w + xv.y * w0k[1].w + xv.z * w0k[2].w + xv.w * w0k[3].w;
            *(float4*)&S[r][j] = h;
            #pragma unroll
            for (int i = 0; i < 4; ++i)
                *(float4*)&S[8 + i * 8 + r][j] = w0k[i];   // J0 rows = W0 rows
        }
    }
    __syncthreads();

    // ---------- 7 hidden blocks: Z = S @ Wh[L]; h=tanh(Z+b); J *= (1-h^2) ----------
    for (int L = 0; L < NLAYER; ++L) {
        const float* WL = Wh + (size_t)L * D * D;
        float4 acc[10][2];
        #pragma unroll
        for (int m = 0; m < 10; ++m) {
            acc[m][0] = make_float4(0.f, 0.f, 0.f, 0.f);
            acc[m][1] = make_float4(0.f, 0.f, 0.f, 0.f);
        }

        float4 stg[8];
        // prologue: stage chunk 0
        #pragma unroll
        for (int ii = 0; ii < 8; ++ii) stg[ii] = ld4(WL + ii * 1024 + t * 4);
        #pragma unroll
        for (int ii = 0; ii < 8; ++ii) ((float4*)Wt[0])[ii * 256 + t] = stg[ii];
        __syncthreads();

        for (int c = 0; c < NCHUNK; ++c) {
            const int cb = c & 1, nb = cb ^ 1;
            // issue next chunk's global loads early (hidden under FMAs)
            if (c + 1 < NCHUNK) {
                const float* src = WL + (size_t)(c + 1) * (BK * D);
                #pragma unroll
                for (int ii = 0; ii < 8; ++ii) stg[ii] = ld4(src + ii * 1024 + t * 4);
            }
            #pragma unroll
            for (int kb = 0; kb < 4; ++kb) {
                float4 sv[10];
                #pragma unroll
                for (int m = 0; m < 10; ++m)
                    sv[m] = ld4(&S[g * 10 + m][c * BK + kb * 4]);   // wave-uniform broadcast
                float4 wv[4][2];
                #pragma unroll
                for (int kk = 0; kk < 4; ++kk)
                    #pragma unroll
                    for (int q = 0; q < 2; ++q)
                        wv[kk][q] = ld4(&Wt[cb][(kb * 4 + kk) * D + lane * 4 + q * 256]);
                #pragma unroll
                for (int m = 0; m < 10; ++m) {
                    const float* sp = (const float*)&sv[m];
                    #pragma unroll
                    for (int kk = 0; kk < 4; ++kk) {
                        const float s = sp[kk];
                        #pragma unroll
                        for (int q = 0; q < 2; ++q) {
                            acc[m][q].x += s * wv[kk][q].x;
                            acc[m][q].y += s * wv[kk][q].y;
                            acc[m][q].z += s * wv[kk][q].z;
                            acc[m][q].w += s * wv[kk][q].w;
                        }
                    }
                }
            }
            // write next chunk; its previous readers finished before last barrier
            if (c + 1 < NCHUNK) {
                #pragma unroll
                for (int ii = 0; ii < 8; ++ii) ((float4*)Wt[nb])[ii * 256 + t] = stg[ii];
            }
            __syncthreads();
        }

        // epilogue phase 1: h rows (owned by wave 0)
        if (g == 0) {
            #pragma unroll
            for (int mi = 0; mi < 8; ++mi)
                #pragma unroll
                for (int q = 0; q < 2; ++q) {
                    const int j = lane * 4 + q * 256;
                    const float4 b = ld4(bh + L * D + j);
                    const float4 z = acc[mi][q];
                    float4 h;
                    h.x = tanhf(z.x + b.x);
                    h.y = tanhf(z.y + b.y);
                    h.z = tanhf(z.z + b.z);
                    h.w = tanhf(z.w + b.w);
                    *(float4*)&S[mi][j] = h;
                }
        }
        __syncthreads();
        // epilogue phase 2: J rows scaled by tanh' = (1 - h_new^2)
        #pragma unroll
        for (int mi = 0; mi < 10; ++mi) {
            const int m = g * 10 + mi;
            if (m >= 8) {
                const int r = (m - 8) & 7;
                #pragma unroll
                for (int q = 0; q < 2; ++q) {
                    const int j = lane * 4 + q * 256;
                    const float4 h = ld4(&S[r][j]);
                    const float4 z = acc[mi][q];
                    float4 o;
                    o.x = z.x * (1.f - h.x * h.x);
                    o.y = z.y * (1.f - h.y * h.y);
                    o.z = z.z * (1.f - h.z * h.z);
                    o.w = z.w * (1.f - h.w * h.w);
                    *(float4*)&S[m][j] = o;
                }
            }
        }
        __syncthreads();
    }

    // ---------- Jout = J7 @ Wf  (4x4 per sample), then curl combination ----------
    if (t < 128) {
        const int r = t >> 4, i = (t >> 2) & 3, jq = t & 3;
        float4 a4 = make_float4(0.f, 0.f, 0.f, 0.f);
        const float* Srow = S[8 + i * 8 + r];
        for (int jj = jq * 128; jj < jq * 128 + 128; jj += 4) {
            const float4 s4 = ld4(Srow + jj);
            const float4 f0 = ld4(Wf + (size_t)(jj + 0) * 4);
            const float4 f1 = ld4(Wf + (size_t)(jj + 1) * 4);
            const float4 f2 = ld4(Wf + (size_t)(jj + 2) * 4);
            const float4 f3 = ld4(Wf + (size_t)(jj + 3) * 4);
            a4.x += s4.x * f0.x + s4.y * f1.x + s4.z * f2.x + s4.w * f3.x;
            a4.y += s4.x * f0.y + s4.y * f1.y + s4.z * f2.y + s4.w * f3.y;
            a4.z += s4.x * f0.z + s4.y * f1.z + s4.z * f2.z + s4.w * f3.z;
            a4.w += s4.x * f0.w + s4.y * f1.w + s4.z * f2.w + s4.w * f3.w;
        }
        a4.x += __shfl_xor(a4.x, 1); a4.y += __shfl_xor(a4.y, 1);
        a4.z += __shfl_xor(a4.z, 1); a4.w += __shfl_xor(a4.w, 1);
        a4.x += __shfl_xor(a4.x, 2); a4.y += __shfl_xor(a4.y, 2);
        a4.z += __shfl_xor(a4.z, 2); a4.w += __shfl_xor(a4.w, 2);
        if (jq == 0) {
            JL[r][i][0] = a4.x; JL[r][i][1] = a4.y;
            JL[r][i][2] = a4.z; JL[r][i][3] = a4.w;
        }
    }
    __syncthreads();
    if (t < 48) {
        const int r = t / 6, c = t - r * 6;
        float v;
        if      (c == 0) v = JL[r][1][2] - JL[r][2][1];
        else if (c == 1) v = JL[r][2][0] - JL[r][0][2];
        else if (c == 2) v = JL[r][0][1] - JL[r][1][0];
        else if (c == 3) v = JL[r][0][3];
        else if (c == 4) v = JL[r][1][3];
        else             v = JL[r][2][3];
        out[(size_t)(n0 + r) * 6 + c] = v;
    }
}

extern "C" void kernel_launch(void* const* d_in, const int* in_sizes, int n_in,
                              void* d_out, int out_size, void* d_ws, size_t ws_size,
                              hipStream_t stream) {
    const float* x  = (const float*)d_in[0];
    const float* W0 = (const float*)d_in[1];
    const float* b0 = (const float*)d_in[2];
    const float* Wh = (const float*)d_in[3];
    const float* bh = (const float*)d_in[4];
    const float* Wf = (const float*)d_in[5];
    float* o = (float*)d_out;
    mlp_curl_fwd<<<NSAMP / RPB, 256, 0, stream>>>(x, W0, b0, Wh, bh, Wf, o);
}

// Round 2
// 6424.226 us; speedup vs baseline: 1.4842x; 1.4842x over previous
//
#include <hip/hip_runtime.h>

#define NSAMP  32768
#define D      512
#define RPB    8          // samples per workgroup
#define NROWS  32         // state rows = 8 h + 24 J (3 Jacobian rows/sample; d/dx3 is never used)
#define BK     16         // k-chunk of streamed weight tile
#define NCHUNK (D / BK)   // 32
#define NLAYER 7          // hidden blocks (WIDTH-1)

__device__ __forceinline__ float4 ld4(const float* p) { return *(const float4*)p; }

__global__ __launch_bounds__(512, 1)
void mlp_curl_fwd(const float* __restrict__ x,
                  const float* __restrict__ W0,
                  const float* __restrict__ b0,
                  const float* __restrict__ Wh,
                  const float* __restrict__ bh,
                  const float* __restrict__ Wf,
                  float* __restrict__ out)
{
    // State rows: r (0..7) = h of sample r; 8 + i*8 + r = J row i (i=0..2) of sample r.
    __shared__ float S[NROWS][D];     // 64 KB
    __shared__ float Wt[2][BK * D];   // 64 KB, double-buffered weight chunk
    __shared__ float JL[RPB][4][4];   // final per-sample Jacobian rows 0..2

    const int t    = threadIdx.x;
    const int g    = t >> 6;          // wave 0..7
    const int lane = t & 63;
    const int rg   = g >> 1;          // row-group 0..3 -> rows rg*8 .. rg*8+7
    const int cg   = g & 1;           // col half
    const int col  = cg * 256 + lane * 4;
    const int n0   = blockIdx.x * RPB;

    // ---------- init: h0 = x@W0 + b0 (NO tanh, faithful); J0 rows = W0 rows 0..2 ----------
    {
        const int r = g;                         // one sample row per wave
        const float4 xv = ld4(x + (size_t)(n0 + r) * 4);
        #pragma unroll
        for (int q = 0; q < 2; ++q) {
            const int j = lane * 4 + q * 256;
            float4 w0k[4];
            #pragma unroll
            for (int k = 0; k < 4; ++k) w0k[k] = ld4(W0 + k * D + j);
            float4 h = ld4(b0 + j);
            h.x += xv.x * w0k[0].x + xv.y * w0k[1].x + xv.z * w0k[2].x + xv.w * w0k[3].x;
            h.y += xv.x * w0k[0].y + xv.y * w0k[1].y + xv.z * w0k[2].y + xv.w * w0k[3].y;
            h.z += xv.x * w0k[0].z + xv.y * w0k[1].z + xv.z * w0k[2].z + xv.w * w0k[3].z;
            h.w += xv.x * w0k[0].w + xv.y * w0k[1].w + xv.z * w0k[2].w + xv.w * w0k[3].w;
            *(float4*)&S[r][j] = h;
            #pragma unroll
            for (int i = 0; i < 3; ++i)
                *(float4*)&S[8 + i * 8 + r][j] = w0k[i];
        }
    }
    __syncthreads();

    // ---------- 7 hidden blocks: Z = S @ Wh[L]; h=tanh(Z+b); J *= (1-h^2) ----------
    for (int L = 0; L < NLAYER; ++L) {
        const float* WL = Wh + (size_t)L * D * D;
        float4 acc[8];
        #pragma unroll
        for (int m = 0; m < 8; ++m) acc[m] = make_float4(0.f, 0.f, 0.f, 0.f);

        float4 stg[4];
        // prologue: stage chunk 0 (BK*D = 8192 floats; 4 float4 per thread)
        #pragma unroll
        for (int ii = 0; ii < 4; ++ii) stg[ii] = ld4(WL + ii * 2048 + t * 4);
        #pragma unroll
        for (int ii = 0; ii < 4; ++ii) ((float4*)Wt[0])[ii * 512 + t] = stg[ii];
        __syncthreads();

        for (int c = 0; c < NCHUNK; ++c) {
            const int cb = c & 1, nb = cb ^ 1;
            if (c + 1 < NCHUNK) {
                const float* src = WL + (size_t)(c + 1) * (BK * D);
                #pragma unroll
                for (int ii = 0; ii < 4; ++ii) stg[ii] = ld4(src + ii * 2048 + t * 4);
            }
            #pragma unroll
            for (int kb = 0; kb < 4; ++kb) {
                float4 sv[8];
                #pragma unroll
                for (int m = 0; m < 8; ++m)
                    sv[m] = ld4(&S[rg * 8 + m][c * BK + kb * 4]);   // wave-uniform broadcast
                float4 wv[4];
                #pragma unroll
                for (int kk = 0; kk < 4; ++kk)
                    wv[kk] = ld4(&Wt[cb][(kb * 4 + kk) * D + col]);
                #pragma unroll
                for (int m = 0; m < 8; ++m) {
                    const float* sp = (const float*)&sv[m];
                    #pragma unroll
                    for (int kk = 0; kk < 4; ++kk) {
                        const float s = sp[kk];
                        acc[m].x += s * wv[kk].x;
                        acc[m].y += s * wv[kk].y;
                        acc[m].z += s * wv[kk].z;
                        acc[m].w += s * wv[kk].w;
                    }
                }
            }
            if (c + 1 < NCHUNK) {
                #pragma unroll
                for (int ii = 0; ii < 4; ++ii) ((float4*)Wt[nb])[ii * 512 + t] = stg[ii];
            }
            __syncthreads();
        }

        // epilogue phase 1: h rows (row-group 0; waves 0,1 cover the two col halves)
        if (rg == 0) {
            #pragma unroll
            for (int m = 0; m < 8; ++m) {
                const float4 b = ld4(bh + L * D + col);
                const float4 z = acc[m];
                float4 h;
                h.x = tanhf(z.x + b.x);
                h.y = tanhf(z.y + b.y);
                h.z = tanhf(z.z + b.z);
                h.w = tanhf(z.w + b.w);
                *(float4*)&S[m][col] = h;
            }
        }
        __syncthreads();
        // epilogue phase 2: J rows scaled by tanh' = (1 - h_new^2)
        if (rg > 0) {
            #pragma unroll
            for (int m = 0; m < 8; ++m) {
                const float4 h = ld4(&S[m][col]);        // h of sample m
                const float4 z = acc[m];
                float4 o;
                o.x = z.x * (1.f - h.x * h.x);
                o.y = z.y * (1.f - h.y * h.y);
                o.z = z.z * (1.f - h.z * h.z);
                o.w = z.w * (1.f - h.w * h.w);
                *(float4*)&S[rg * 8 + m][col] = o;
            }
        }
        __syncthreads();
    }

    // ---------- Jout rows 0..2 = J7 @ Wf, then curl combination ----------
    {
        // t = pair*16 + jq : pair -> (r, i), 16 lanes split k into 32-wide segments
        const int jq   = t & 15;
        const int pair = t >> 4;
        const int r    = pair >> 2;
        const int i    = pair & 3;
        float4 a4 = make_float4(0.f, 0.f, 0.f, 0.f);
        if (i < 3) {
            const float* Srow = S[8 + i * 8 + r];
            for (int jj = jq * 32; jj < jq * 32 + 32; jj += 4) {
                const float4 s4 = ld4(Srow + jj);
                const float4 f0 = ld4(Wf + (size_t)(jj + 0) * 4);
                const float4 f1 = ld4(Wf + (size_t)(jj + 1) * 4);
                const float4 f2 = ld4(Wf + (size_t)(jj + 2) * 4);
                const float4 f3 = ld4(Wf + (size_t)(jj + 3) * 4);
                a4.x += s4.x * f0.x + s4.y * f1.x + s4.z * f2.x + s4.w * f3.x;
                a4.y += s4.x * f0.y + s4.y * f1.y + s4.z * f2.y + s4.w * f3.y;
                a4.z += s4.x * f0.z + s4.y * f1.z + s4.z * f2.z + s4.w * f3.z;
                a4.w += s4.x * f0.w + s4.y * f1.w + s4.z * f2.w + s4.w * f3.w;
            }
        }
        #pragma unroll
        for (int m = 1; m <= 8; m <<= 1) {
            a4.x += __shfl_xor(a4.x, m);
            a4.y += __shfl_xor(a4.y, m);
            a4.z += __shfl_xor(a4.z, m);
            a4.w += __shfl_xor(a4.w, m);
        }
        if (jq == 0 && i < 3) {
            JL[r][i][0] = a4.x; JL[r][i][1] = a4.y;
            JL[r][i][2] = a4.z; JL[r][i][3] = a4.w;
        }
    }
    __syncthreads();
    if (t < 48) {
        const int r = t / 6, c = t - r * 6;
        float v;
        if      (c == 0) v = JL[r][1][2] - JL[r][2][1];
        else if (c == 1) v = JL[r][2][0] - JL[r][0][2];
        else if (c == 2) v = JL[r][0][1] - JL[r][1][0];
        else if (c == 3) v = JL[r][0][3];
        else if (c == 4) v = JL[r][1][3];
        else             v = JL[r][2][3];
        out[(size_t)(n0 + r) * 6 + c] = v;
    }
}

extern "C" void kernel_launch(void* const* d_in, const int* in_sizes, int n_in,
                              void* d_out, int out_size, void* d_ws, size_t ws_size,
                              hipStream_t stream) {
    const float* x  = (const float*)d_in[0];
    const float* W0 = (const float*)d_in[1];
    const float* b0 = (const float*)d_in[2];
    const float* Wh = (const float*)d_in[3];
    const float* bh = (const float*)d_in[4];
    const float* Wf = (const float*)d_in[5];
    float* o = (float*)d_out;
    mlp_curl_fwd<<<NSAMP / RPB, 512, 0, stream>>>(x, W0, b0, Wh, bh, Wf, o);
}

// Round 3
// 3881.995 us; speedup vs baseline: 2.4562x; 1.6549x over previous
//
#include <hip/hip_runtime.h>
#include <stdint.h>

typedef short bf16x8 __attribute__((ext_vector_type(8)));
typedef float f32x4  __attribute__((ext_vector_type(4)));
typedef uint32_t u32;

#define NSAMP  32768
#define D      512
#define RPB    16
#define NLAYER 7
#define KSN    16                    // K-slices of 32 per layer
#define WL_U32 131072                // u32 per packed layer (16*512*4half*4u32)

union U4B { uint4 u; u32 w[4]; bf16x8 s; };
__device__ __forceinline__ bf16x8 as_frag(uint4 v) { U4B c; c.u = v; return c.s; }
__device__ __forceinline__ bf16x8 as_frag4(u32 a, u32 b, u32 c2, u32 d) {
    U4B c; c.w[0] = a; c.w[1] = b; c.w[2] = c2; c.w[3] = d; return c.s;
}

__device__ __forceinline__ u32 bfr(float f) {               // RNE bf16 bits
    u32 b = __float_as_uint(f);
    return (b + 0x7fffu + ((b >> 16) & 1u)) >> 16;
}
__device__ __forceinline__ float bf2f(u32 h) { return __uint_as_float(h << 16); }
__device__ __forceinline__ u32 packpair(float v) {          // hi | lo<<16
    u32 h = bfr(v);
    u32 l = bfr(v - bf2f(h));
    return h | (l << 16);
}
__device__ __forceinline__ u32 swz(int row, u32 byte) { return byte ^ ((u32)(row & 7) << 4); }

// ---- prep: pack Wh[L][k][n] -> B-fragment-ordered bf16 hi/lo tensors ----
// layout: 16B unit idx4 = ((L*16+ks)*512 + n)*4 + half ; holds k = ks*32+half*8+{0..7}, col n
__global__ void pack_weights(const float* __restrict__ Wh,
                             u32* __restrict__ whi, u32* __restrict__ wlo) {
    const int L    = blockIdx.x >> 4;
    const int ks   = blockIdx.x & 15;
    const int lane = threadIdx.x & 63;
    const int half = threadIdx.x >> 6;                       // 0..3
    const float* src = Wh + (size_t)L * D * D + (size_t)(ks * 32 + half * 8) * D;
    for (int nb = 0; nb < D; nb += 64) {
        const int n = nb + lane;
        float v[8];
        #pragma unroll
        for (int i = 0; i < 8; ++i) v[i] = src[(size_t)i * D + n];
        u32 hi[4], lo[4];
        #pragma unroll
        for (int j = 0; j < 4; ++j) {
            u32 h0 = bfr(v[2*j]),   l0 = bfr(v[2*j]   - bf2f(h0));
            u32 h1 = bfr(v[2*j+1]), l1 = bfr(v[2*j+1] - bf2f(h1));
            hi[j] = h0 | (h1 << 16);
            lo[j] = l0 | (l1 << 16);
        }
        const size_t idx4 = (size_t)((L * 16 + ks) * 512 + n) * 4 + half;
        *(uint4*)(whi + idx4 * 4) = *(uint4*)hi;
        *(uint4*)(wlo + idx4 * 4) = *(uint4*)lo;
    }
}

// ---- main: fused MLP forward + 3-row input Jacobian via split-bf16 MFMA ----
__global__ __launch_bounds__(512)
void mlp_curl_mfma(const float* __restrict__ x,
                   const float* __restrict__ W0,
                   const float* __restrict__ b0,
                   const float* __restrict__ bhid,
                   const float* __restrict__ Wf,
                   const u32* __restrict__ whi,
                   const u32* __restrict__ wlo,
                   float* __restrict__ out)
{
    // rows 0-15: h (samples 0-15); 16-31: J0; 32-47: J1; 48-63: J2
    __shared__ u32  Sp[64][512];      // 128 KB: (hi|lo<<16) bf16 pairs, swizzled
    __shared__ float Tt[16][512];     //  32 KB: tanh' fp32, swizzled

    const int t    = threadIdx.x;
    const int g    = t >> 6, lane = t & 63;
    const int rg   = g >> 1, cg = g & 1;
    const int r0   = rg << 4;                 // wave's row-tile base
    const int nb   = cg << 8;                 // wave's col base (256 cols)
    const int lrow = lane & 15, lq = lane >> 4;
    const int n0   = blockIdx.x * RPB;

    // ---------- init: h0 = x@W0 + b0 (no tanh); J0 rows = W0 rows 0..2 ----------
    {
        const int c0 = lane << 3;             // 8 cols per lane
        #pragma unroll
        for (int rr = 0; rr < 8; ++rr) {
            const int row = (g << 3) + rr;
            float v[8];
            if (row < 16) {
                const float4 xv = *(const float4*)(x + (size_t)(n0 + row) * 4);
                #pragma unroll
                for (int i = 0; i < 8; ++i)
                    v[i] = b0[c0 + i]
                         + xv.x * W0[c0 + i]       + xv.y * W0[D + c0 + i]
                         + xv.z * W0[2*D + c0 + i] + xv.w * W0[3*D + c0 + i];
            } else {
                const int ir = (row >> 4) - 1;
                #pragma unroll
                for (int i = 0; i < 8; ++i) v[i] = W0[ir * D + c0 + i];
            }
            u32 pr[8];
            #pragma unroll
            for (int i = 0; i < 8; ++i) pr[i] = packpair(v[i]);
            char* base = (char*)&Sp[row][0];
            *(uint4*)(base + swz(row, (u32)(c0 << 2)))      = *(uint4*)&pr[0];
            *(uint4*)(base + swz(row, (u32)(c0 << 2) + 16)) = *(uint4*)&pr[4];
        }
    }
    __syncthreads();

    const u32 bvoff = ((u32)(nb + lrow) * 4 + lq) * 4;   // per-lane B offset in a ks-slab (u32)

    for (int L = 0; L < NLAYER; ++L) {
        f32x4 acc[16];
        #pragma unroll
        for (int i = 0; i < 16; ++i) acc[i] = (f32x4)0.f;

        const u32* __restrict__ whiL = whi + (size_t)L * WL_U32;
        const u32* __restrict__ wloL = wlo + (size_t)L * WL_U32;

        for (int ks = 0; ks < KSN; ++ks) {
            // A fragments from LDS (swizzled, 2-way max conflict)
            u32 p[8];
            {
                const int arow = r0 + lrow;
                char* base = (char*)&Sp[arow][0];
                const u32 ab = (u32)(ks << 7) + (u32)(lq << 5);
                *(uint4*)&p[0] = *(const uint4*)(base + swz(arow, ab));
                *(uint4*)&p[4] = *(const uint4*)(base + swz(arow, ab + 16));
            }
            u32 ah[4], al[4];
            #pragma unroll
            for (int j = 0; j < 4; ++j) {
                ah[j] = (p[2*j] & 0xffffu) | (p[2*j+1] << 16);
                al[j] = (p[2*j] >> 16)     | (p[2*j+1] & 0xffff0000u);
            }
            const bf16x8 a_hi = as_frag4(ah[0], ah[1], ah[2], ah[3]);
            const bf16x8 a_lo = as_frag4(al[0], al[1], al[2], al[3]);

            // B fragments: 32 coalesced 16B global loads (L2-resident packed weights)
            const u32* bp_h = whiL + (size_t)ks * 8192 + bvoff;
            const u32* bp_l = wloL + (size_t)ks * 8192 + bvoff;
            uint4 Bh[16], Bl[16];
            #pragma unroll
            for (int nt = 0; nt < 16; ++nt) {
                Bh[nt] = *(const uint4*)(bp_h + nt * 256);
                Bl[nt] = *(const uint4*)(bp_l + nt * 256);
            }
            #pragma unroll
            for (int nt = 0; nt < 16; ++nt) {
                const bf16x8 bhf = as_frag(Bh[nt]);
                const bf16x8 blf = as_frag(Bl[nt]);
                acc[nt] = __builtin_amdgcn_mfma_f32_16x16x32_bf16(a_lo, bhf, acc[nt], 0, 0, 0);
                acc[nt] = __builtin_amdgcn_mfma_f32_16x16x32_bf16(a_hi, blf, acc[nt], 0, 0, 0);
                acc[nt] = __builtin_amdgcn_mfma_f32_16x16x32_bf16(a_hi, bhf, acc[nt], 0, 0, 0);
            }
        }

        __syncthreads();                       // all Sp reads for layer L done
        if (rg == 0) {
            // h-phase: rows 0-15. z+bias -> tanh -> Sp pairs + T=1-h^2
            const float* bhL = bhid + (size_t)L * D;
            #pragma unroll
            for (int nt = 0; nt < 16; ++nt) {
                const int col = nb + (nt << 4) + lrow;
                const float bias = bhL[col];
                #pragma unroll
                for (int q = 0; q < 4; ++q) {
                    const int row = (lq << 2) + q;           // == sample
                    const float z = acc[nt][q] + bias;
                    const float h = tanhf(z);
                    *(float*)((char*)&Tt[row][0] + swz(row, (u32)col << 2)) = 1.f - h * h;
                    if (L < NLAYER - 1)
                        *(u32*)((char*)&Sp[row][0] + swz(row, (u32)col << 2)) = packpair(h);
                }
            }
        }
        __syncthreads();                       // T (and h rows) ready
        if (rg > 0) {
            if (L < NLAYER - 1) {
                // J-phase: scale by tanh', write pairs back
                #pragma unroll
                for (int nt = 0; nt < 16; ++nt) {
                    const int col = nb + (nt << 4) + lrow;
                    #pragma unroll
                    for (int q = 0; q < 4; ++q) {
                        const int s = (lq << 2) + q;
                        const int row = r0 + s;
                        const float tp = *(const float*)((char*)&Tt[s][0] + swz(s, (u32)col << 2));
                        *(u32*)((char*)&Sp[row][0] + swz(row, (u32)col << 2)) = packpair(acc[nt][q] * tp);
                    }
                }
            } else {
                // final layer: Jout = (Z_J * tanh') @ Wf, reduced in-register
                float part[4][4];
                #pragma unroll
                for (int q = 0; q < 4; ++q)
                    #pragma unroll
                    for (int o = 0; o < 4; ++o) part[q][o] = 0.f;
                #pragma unroll
                for (int nt = 0; nt < 16; ++nt) {
                    const int col = nb + (nt << 4) + lrow;
                    const float4 wf = *(const float4*)(Wf + (size_t)col * 4);
                    #pragma unroll
                    for (int q = 0; q < 4; ++q) {
                        const int s = (lq << 2) + q;
                        const float tp = *(const float*)((char*)&Tt[s][0] + swz(s, (u32)col << 2));
                        const float jv = acc[nt][q] * tp;
                        part[q][0] += jv * wf.x;
                        part[q][1] += jv * wf.y;
                        part[q][2] += jv * wf.z;
                        part[q][3] += jv * wf.w;
                    }
                }
                #pragma unroll
                for (int m = 1; m < 16; m <<= 1)
                    #pragma unroll
                    for (int q = 0; q < 4; ++q)
                        #pragma unroll
                        for (int o = 0; o < 4; ++o)
                            part[q][o] += __shfl_xor(part[q][o], m);
                if (lrow == 0) {
                    float* JT = (float*)Sp;                  // Sp dead at final layer
                    const int jrow = (r0 - 16) + (lq << 2);  // i*16 + s, 0..47
                    #pragma unroll
                    for (int q = 0; q < 4; ++q)
                        #pragma unroll
                        for (int o = 0; o < 4; ++o)
                            JT[(size_t)(jrow + q) * 8 + (cg << 2) + o] = part[q][o];
                }
            }
        }
        __syncthreads();
    }

    // ---------- curl combination ----------
    if (t < RPB * 6) {
        const float* JT = (const float*)Sp;
        const int s = t / 6, c = t % 6;
        #define JJ(i, o) (JT[(size_t)((i)*16 + s) * 8 + (o)] + JT[(size_t)((i)*16 + s) * 8 + 4 + (o)])
        float v;
        if      (c == 0) v = JJ(1,2) - JJ(2,1);
        else if (c == 1) v = JJ(2,0) - JJ(0,2);
        else if (c == 2) v = JJ(0,1) - JJ(1,0);
        else if (c == 3) v = JJ(0,3);
        else if (c == 4) v = JJ(1,3);
        else             v = JJ(2,3);
        #undef JJ
        out[(size_t)(n0 + s) * 6 + c] = v;
    }
}

extern "C" void kernel_launch(void* const* d_in, const int* in_sizes, int n_in,
                              void* d_out, int out_size, void* d_ws, size_t ws_size,
                              hipStream_t stream) {
    const float* x  = (const float*)d_in[0];
    const float* W0 = (const float*)d_in[1];
    const float* b0 = (const float*)d_in[2];
    const float* Wh = (const float*)d_in[3];
    const float* bh = (const float*)d_in[4];
    const float* Wf = (const float*)d_in[5];
    u32* whi = (u32*)d_ws;
    u32* wlo = whi + (size_t)NLAYER * WL_U32;         // 3.67 MB each, 7.34 MB total in ws
    pack_weights<<<NLAYER * 16, 256, 0, stream>>>(Wh, whi, wlo);
    mlp_curl_mfma<<<NSAMP / RPB, 512, 0, stream>>>(x, W0, b0, bh, Wf, whi, wlo, (float*)d_out);
}